// Round 10
// baseline (2770.932 us; speedup 1.0000x reference)
//
#include <hip/hip_runtime.h>

// Dims fixed by the reference
#define LAY 2
#define BATCH 64
#define TMAX 512
#define DIM 256
#define AST 264   // LDS activation row stride (bytes, fp8)

typedef float floatx4 __attribute__((ext_vector_type(4)));
typedef __bf16 bf16x8 __attribute__((ext_vector_type(8)));
#define MFMA_FP8  __builtin_amdgcn_mfma_f32_16x16x32_fp8_fp8
#define MFMA_BF16 __builtin_amdgcn_mfma_f32_16x16x32_bf16

// Opaque volatile def: compiler cannot re-materialize x by sinking its load
// into the loop (the R2/R3/R6/R9 pathology, proven by R9's VGPR_Count=60).
#define PIN(x) asm volatile("" : "+v"(x))

// d_ws layout (requires ws >= ~74 MB)
#define OFF_WPW 0x60000     // bf16 B-frag W-mats, 6 x 128 KB
#define OFF_XP  0x200000    // layer-0 X-projections fp8, 25.2 MB
#define OFF_HP  0x1C00000   // layer-1 input projections fp8, 25.2 MB
#define OFF_HN  0x3600000   // hn0 bf16 [b*512+t][256], 16.8 MB

__device__ __forceinline__ unsigned short f2bf(float f) {
    unsigned int u = __float_as_uint(f);
    unsigned int r = u + 0x7fffu + ((u >> 16) & 1u);  // RNE
    return (unsigned short)(r >> 16);
}
__device__ __forceinline__ unsigned int pk2(float a, float b) {
    return (unsigned int)__builtin_amdgcn_cvt_pk_fp8_f32(a, b, 0, false);  // OCP e4m3 x2
}
__device__ __forceinline__ unsigned char f2q(float a) { return (unsigned char)(pk2(a, a) & 0xff); }
__device__ __forceinline__ void unp4(unsigned int u, float* f) {
    auto lo = __builtin_amdgcn_cvt_pk_f32_fp8((int)u, false);
    auto hi = __builtin_amdgcn_cvt_pk_f32_fp8((int)u, true);
    f[0] = lo[0]; f[1] = lo[1]; f[2] = hi[0]; f[3] = hi[1];
}
__device__ __forceinline__ float sigf(float x) { return 1.f / (1.f + __expf(-x)); }
// tanh(y) = 2*sigmoid(2y) - 1
__device__ __forceinline__ float tanhfast2y(float twoy) { return 2.f * sigf(twoy) - 1.f; }

// ---------------------------------------------------------------------------
// Weight prep (identical to R8/R9). U-mats fp8 e4m3 x8 (mu=l*3+g):
//   byte ((mu*16+nt)*4+kp)*1024 + lane*16 + half*8 + j ->
//     8*U[k=(2kp+half)*32+(lane>>4)*8+j][n=nt*16+(lane&15)]
// W-mats bf16 B-frags (mw=l*3+g):
//   byte ((mw*16+nt)*8+kf)*1024 + lane*16 + 2j ->
//     bf16 W[k=kf*32+(lane>>4)*8+j][n=nt*16+(lane&15)]
// Also zeroes d_out.
// ---------------------------------------------------------------------------
__global__ void prep_weights(const float* __restrict__ Wz, const float* __restrict__ Wr,
                             const float* __restrict__ Wh, const float* __restrict__ Uz,
                             const float* __restrict__ Ur, const float* __restrict__ Uh,
                             unsigned char* __restrict__ ws, float* __restrict__ out) {
    int T = blockIdx.x * 256 + threadIdx.x;  // 1536*256 = 393216
    if (T == 0) out[0] = 0.f;
    if (T < 196608) {  // U-mats, fp8
        int e = T & 3, half = (T >> 2) & 1, lane = (T >> 3) & 63;
        int kp = (T >> 9) & 3, nt = (T >> 11) & 15, mu = T >> 15;
        int g = mu % 3, l = mu / 3;
        const float* s = (g == 0 ? Uz : g == 1 ? Ur : Uh) + l * 65536;
        int n  = nt * 16 + (lane & 15);
        int k0 = (2 * kp + half) * 32 + (lane >> 4) * 8 + 2 * e;
        float w0 = s[(k0 << 8) + n] * 8.f;        // x8: dodge e4m3 denormals
        float w1 = s[((k0 + 1) << 8) + n] * 8.f;  // undone by 0.125 post-acc
        int addr = ((mu * 16 + nt) * 4 + kp) * 1024 + lane * 16 + half * 8 + 2 * e;
        *(unsigned short*)(ws + addr) = (unsigned short)(pk2(w0, w1) & 0xffff);
    } else {           // W-mats, bf16
        int T2 = T - 196608;
        int e = T2 & 3, lane = (T2 >> 2) & 63;
        int kf = (T2 >> 8) & 7, nt = (T2 >> 11) & 15, mw = T2 >> 15;
        int g = mw % 3, l = mw / 3;
        const float* s = (g == 0 ? Wz : g == 1 ? Wr : Wh) + l * 65536;
        int n  = nt * 16 + (lane & 15);
        int k0 = kf * 32 + (lane >> 4) * 8 + 2 * e;
        unsigned int v = (unsigned int)f2bf(s[(k0 << 8) + n]) |
                         ((unsigned int)f2bf(s[((k0 + 1) << 8) + n]) << 16);
        int addr = ((mw * 16 + nt) * 8 + kf) * 1024 + lane * 16 + 4 * e;
        *(unsigned int*)(ws + OFF_WPW + addr) = v;
    }
}

// ---------------------------------------------------------------------------
// Projection GEMM (identical to R8/R9). Grid 2048 = bg*512+t; wave = col tile.
// Output fp8(x16) lane-natural: xp[(bgt*48 + g*16 + w)*64 + lane]
// ---------------------------------------------------------------------------
template <int F32SRC>
__global__ __launch_bounds__(1024) void proj_kernel(const void* __restrict__ src,
                                                    const unsigned char* __restrict__ wpW,
                                                    unsigned int* __restrict__ xpo, int matbase) {
    const int bgt = blockIdx.x;
    const int t = bgt & 511, bg = bgt >> 9;
    const int tid = threadIdx.x, wave = tid >> 6, lane = tid & 63;
    const int l15 = lane & 15, quad = lane >> 4;
    const size_t rowoff = ((size_t)(bg * 16 + l15) * 512 + t) * 256;

    bf16x8 af[8];
    if (F32SRC) {
        const float* s = (const float*)src + rowoff;
#pragma unroll
        for (int kf = 0; kf < 8; ++kf) {
            float4 a = *(const float4*)(s + kf * 32 + quad * 8);
            float4 b = *(const float4*)(s + kf * 32 + quad * 8 + 4);
            union { unsigned short u[8]; bf16x8 v; } cv;
            cv.u[0] = f2bf(a.x); cv.u[1] = f2bf(a.y); cv.u[2] = f2bf(a.z); cv.u[3] = f2bf(a.w);
            cv.u[4] = f2bf(b.x); cv.u[5] = f2bf(b.y); cv.u[6] = f2bf(b.z); cv.u[7] = f2bf(b.w);
            af[kf] = cv.v;
        }
    } else {
        const unsigned short* s = (const unsigned short*)src + rowoff;
#pragma unroll
        for (int kf = 0; kf < 8; ++kf) af[kf] = *(const bf16x8*)(s + kf * 32 + quad * 8);
    }

    floatx4 az = {0.f, 0.f, 0.f, 0.f}, ar = az, ah = az;
    const unsigned char* bz = wpW + (size_t)(((matbase + 0) * 16 + wave) * 8) * 1024 + lane * 16;
    const unsigned char* br = wpW + (size_t)(((matbase + 1) * 16 + wave) * 8) * 1024 + lane * 16;
    const unsigned char* bh = wpW + (size_t)(((matbase + 2) * 16 + wave) * 8) * 1024 + lane * 16;
#pragma unroll
    for (int kf = 0; kf < 8; ++kf) {
        az = MFMA_BF16(af[kf], *(const bf16x8*)(bz + kf * 1024), az, 0, 0, 0);
        ar = MFMA_BF16(af[kf], *(const bf16x8*)(br + kf * 1024), ar, 0, 0, 0);
        ah = MFMA_BF16(af[kf], *(const bf16x8*)(bh + kf * 1024), ah, 0, 0, 0);
    }
    const size_t ob = (size_t)bgt * 3072 + wave * 64 + lane;
    xpo[ob]        = pk2(16.f * az[0], 16.f * az[1]) | (pk2(16.f * az[2], 16.f * az[3]) << 16);
    xpo[ob + 1024] = pk2(16.f * ar[0], 16.f * ar[1]) | (pk2(16.f * ar[2], 16.f * ar[3]) << 16);
    xpo[ob + 2048] = pk2(16.f * ah[0], 16.f * ah[1]) | (pk2(16.f * ah[2], 16.f * ah[3]) << 16);
}

// ---------------------------------------------------------------------------
// Recurrence: 4 WGs x 16 rows, 16 waves x 1 col-tile (nt = wave). U-weights
// loaded ONCE and PINNED in VGPRs (volatile asm defs). z-sigmoid deferred to
// phase 2; fast tanh. SCORE=1: wave w scores row w (distributed).
// ---------------------------------------------------------------------------
template <int SCORE>
__global__ __launch_bounds__(1024, 4) void recur_kernel(const unsigned int* __restrict__ xp,
                                                        const unsigned char* __restrict__ wpU,
                                                        int lbase,
                                                        unsigned short* __restrict__ hnout,
                                                        const int* __restrict__ xlen,
                                                        const float* __restrict__ xlab,
                                                        const float* __restrict__ Wo,
                                                        float* __restrict__ out) {
    __shared__ __align__(16) unsigned char s1q[16][AST];
    __shared__ __align__(16) unsigned char rsq[16][AST];
    __shared__ __align__(16) float s1o[16][264];
    __shared__ float wo1s[DIM];

    const int tid = threadIdx.x, wave = tid >> 6, lane = tid & 63;
    const int l15 = lane & 15, quad = lane >> 4;
    const int bg = blockIdx.x, b0 = bg * 16;

    for (int i = tid; i < 16 * AST; i += 1024) ((unsigned char*)s1q)[i] = 0;
    if (SCORE && tid < DIM) wo1s[tid] = Wo[2 * tid + 1];
    const int lenw = SCORE ? xlen[b0 + wave] : 0;       // wave-uniform
    const float labw = SCORE ? xlab[b0 + wave] : 0.f;
    int v = xlen[b0 + l15];
#pragma unroll
    for (int o = 1; o < 16; o <<= 1) v = max(v, __shfl_xor(v, o));
    const int tmax = __builtin_amdgcn_readfirstlane(v);

    const int nt = wave;
    const int colA = nt * 16 + l15, rowb = quad * 4;

    // U fragments: load once, then PIN so the compiler cannot sink the loads
    // back into the t-loop (R9's VGPR_Count=60 proved it does exactly that).
    long uz[8], ur[8], uh[8];
    {
        const unsigned char* pz = wpU + (size_t)(((lbase + 0) * 16 + nt) * 4) * 1024 + lane * 16;
        const unsigned char* pr = wpU + (size_t)(((lbase + 1) * 16 + nt) * 4) * 1024 + lane * 16;
        const unsigned char* ph = wpU + (size_t)(((lbase + 2) * 16 + nt) * 4) * 1024 + lane * 16;
#pragma unroll
        for (int kf = 0; kf < 8; ++kf) {
            int o = (kf >> 1) * 1024 + (kf & 1) * 8;
            uz[kf] = *(const long*)(pz + o);
            ur[kf] = *(const long*)(pr + o);
            uh[kf] = *(const long*)(ph + o);
        }
#pragma unroll
        for (int kf = 0; kf < 8; ++kf) { PIN(uz[kf]); PIN(ur[kf]); PIN(uh[kf]); }
    }
    float s1r[4] = {};
    float accl = 0.f;
    __syncthreads();

    float4 wo1r;
    if (SCORE) wo1r = *(const float4*)&wo1s[lane * 4];

    for (int t = 0; t < tmax; ++t) {
        const unsigned int* xpt = xp + (size_t)(bg * 512 + t) * 3072 + lane;
        unsigned int xz = xpt[nt * 64];
        unsigned int xr = xpt[1024 + nt * 64];
        unsigned int xh = xpt[2048 + nt * 64];

        // ---- phase 1: r (critical path) + z-MFMAs (acc crosses the barrier) ----
        long sf[8];
#pragma unroll
        for (int kf = 0; kf < 8; ++kf) sf[kf] = *(const long*)&s1q[l15][kf * 32 + quad * 8];
        floatx4 za = {0.f, 0.f, 0.f, 0.f}, ra = za;
#pragma unroll
        for (int kf = 0; kf < 8; ++kf) {
            ra = MFMA_FP8(sf[kf], ur[kf], ra, 0, 0, 0);
            za = MFMA_FP8(sf[kf], uz[kf], za, 0, 0, 0);
        }
        float xrf[4];
        unp4(xr, xrf);
#pragma unroll
        for (int i = 0; i < 4; ++i) {
            float r = sigf(0.125f * ra[i] + 0.0625f * xrf[i]);
            rsq[rowb + i][colA] = f2q(r * s1r[i]);
        }
        __syncthreads();

        // ---- phase 2: h; z-sigmoid overlaps the Uh MFMA ----
        long rf[8];
#pragma unroll
        for (int kf = 0; kf < 8; ++kf) rf[kf] = *(const long*)&rsq[l15][kf * 32 + quad * 8];
        floatx4 ha = {0.f, 0.f, 0.f, 0.f};
#pragma unroll
        for (int kf = 0; kf < 8; ++kf) ha = MFMA_FP8(rf[kf], uh[kf], ha, 0, 0, 0);
        float xzf[4], xhf[4];
        unp4(xz, xzf); unp4(xh, xhf);
#pragma unroll
        for (int i = 0; i < 4; ++i) {
            float z = sigf(0.125f * za[i] + 0.0625f * xzf[i]);
            float h = tanhfast2y(0.25f * ha[i] + 0.125f * xhf[i]);  // tanh(0.125ha+0.0625xh)
            float hn = (1.f - z) * s1r[i] + z * h;
            s1r[i] = hn;
            s1q[rowb + i][colA] = f2q(hn);
            s1o[rowb + i][colA] = hn;
        }
        __syncthreads();

        if (!SCORE) {
            // cooperative hn0 write: row=tid>>6, 4 cols/thread; coalesced 8B stores
            const int r = tid >> 6, c = (tid & 63) * 4;
            float4 f0 = *(const float4*)&s1o[r][c];
            uint2 o2;
            o2.x = f2bf(f0.x) | ((unsigned)f2bf(f0.y) << 16);
            o2.y = f2bf(f0.z) | ((unsigned)f2bf(f0.w) << 16);
            *(uint2*)(hnout + ((size_t)(b0 + r) * 512 + t) * 256 + c) = o2;
        } else {
            // distributed score: wave w scores row w (1 b128 read + 4 fma + 6 shfl)
            float4 sv = *(const float4*)&s1o[wave][lane * 4];
            float p = sv.x * wo1r.x;
            p = fmaf(sv.y, wo1r.y, p);
            p = fmaf(sv.z, wo1r.z, p);
            p = fmaf(sv.w, wo1r.w, p);
            p += __shfl_xor(p, 1);  p += __shfl_xor(p, 2);  p += __shfl_xor(p, 4);
            p += __shfl_xor(p, 8);  p += __shfl_xor(p, 16); p += __shfl_xor(p, 32);
            if (lane == 0 && t < lenw) {
                float sc = sigf(p);
                float d = labw - sc;
                accl = fmaf(d, d, accl);
            }
        }
    }

    if (SCORE && lane == 0) atomicAdd(out, accl);  // one atomic per wave
}

extern "C" void kernel_launch(void* const* d_in, const int* in_sizes, int n_in,
                              void* d_out, int out_size, void* d_ws, size_t ws_size,
                              hipStream_t stream) {
    const float* x    = (const float*)d_in[0];
    const int*   xlen = (const int*)d_in[1];
    const float* xlab = (const float*)d_in[2];
    const float* Wz   = (const float*)d_in[3];
    const float* Uz   = (const float*)d_in[4];
    const float* Wr   = (const float*)d_in[5];
    const float* Ur   = (const float*)d_in[6];
    const float* Wh   = (const float*)d_in[7];
    const float* Uh   = (const float*)d_in[8];
    const float* Wo   = (const float*)d_in[9];
    float* out = (float*)d_out;

    unsigned char* ws  = (unsigned char*)d_ws;
    unsigned char* wpU = ws;                                 // fp8 U-frags, 384 KB
    unsigned char* wpW = ws + OFF_WPW;                       // bf16 W-frags, 768 KB
    unsigned int*  XP  = (unsigned int*)(ws + OFF_XP);       // 25.2 MB
    unsigned int*  HP  = (unsigned int*)(ws + OFF_HP);       // 25.2 MB
    unsigned short* HN = (unsigned short*)(ws + OFF_HN);     // 16.8 MB

    // ws re-poisoned every call -> rebuild everything each time.
    prep_weights<<<1536, 256, 0, stream>>>(Wz, Wr, Wh, Uz, Ur, Uh, ws, out);
    proj_kernel<1><<<2048, 1024, 0, stream>>>(x, wpW, XP, 0);                         // A: x @ W(l0)
    recur_kernel<0><<<4, 1024, 0, stream>>>(XP, wpU, 0, HN, xlen, xlab, Wo, out);     // B: layer-0 scan
    proj_kernel<0><<<2048, 1024, 0, stream>>>(HN, wpW, HP, 3);                        // C: hn0 @ W(l1)
    recur_kernel<1><<<4, 1024, 0, stream>>>(HP, wpU, 3, nullptr, xlen, xlab, Wo, out);// D: layer-1 + loss
}